// Round 2
// baseline (164.186 us; speedup 1.0000x reference)
//
#include <hip/hip_runtime.h>

typedef __attribute__((ext_vector_type(8))) short short8;
typedef __attribute__((ext_vector_type(4))) float f32x4;

__device__ __forceinline__ unsigned short f2b(float x) {
  union { float f; unsigned u; } v; v.f = x;
  unsigned r = v.u + 0x7fffu + ((v.u >> 16) & 1u);
  return (unsigned short)(r >> 16);
}

// ---- prep: transpose + bf16-convert weights into workspace ----
// Source-coalesced: thread t reads source linearly, writes strided (writes
// are fire-and-forget; strided READS were the latency cost).
// W1T [512][128]: rows 0..255 = Wv^T; rows 256..511 = Wg^T with columns
// pre-permuted so gate channel for output c=h*64+d is at row 256+c
// (gate source col g = d*4+h  =>  dest row 256 + (g&3)*64 + (g>>2)).
// WoT [128][256] = Wo^T.  bg2[256] = permuted gate bias.
__global__ __launch_bounds__(256) void prep_kernel(
    const float* __restrict__ Wv, const float* __restrict__ Wg,
    const float* __restrict__ bgv, const float* __restrict__ Wo,
    unsigned short* __restrict__ W1T, unsigned short* __restrict__ WoT,
    float* __restrict__ bg2)
{
  int t = blockIdx.x * 256 + threadIdx.x;
  if (t < 32768) {                      // Wv: src [e][c], e=t>>8, c=t&255
    int e = t >> 8, c = t & 255;
    W1T[c * 128 + e] = f2b(Wv[t]);
  } else if (t < 65536) {               // Wg: src [e][g]
    int s = t - 32768;
    int e = s >> 8, g = s & 255;
    int cc = ((g & 3) << 6) + (g >> 2); // cc = h*64+d
    W1T[(256 + cc) * 128 + e] = f2b(Wg[s]);
  } else if (t < 65536 + 32768) {       // Wo: src [c][o]
    int s = t - 65536;
    int c = s >> 7, o = s & 127;
    WoT[o * 256 + c] = f2b(Wo[s]);
  } else if (t < 65536 + 32768 + 256) {
    int g = t - (65536 + 32768);
    bg2[((g & 3) << 6) + (g >> 2)] = bgv[g];
  }
}

// ---- fused: per 64-row tile: V/G GEMM -> sigmoid*V -> @Wo + bo ----
// LDS overlay: Xs (16KB) is dead once A-fragments are in registers, so Ys
// (32KB) reuses the same buffer => 32KB/block => 5 blocks/CU (vs 3 at 48KB).
__global__ __launch_bounds__(256, 5) void fused_kernel(
    const float* __restrict__ X,              // [65536][128] f32
    const unsigned short* __restrict__ W1T,   // [512][128] bf16
    const unsigned short* __restrict__ WoT,   // [128][256] bf16
    const float* __restrict__ bg2,            // [256]
    const float* __restrict__ bo,             // [128]
    float* __restrict__ Out)                  // [65536][128] f32
{
  __shared__ unsigned short smem[64 * 256];   // 32KB, overlaid
  unsigned short* Xs = smem;                  // [64][128] bf16, XOR-swizzled
  unsigned short* Ys = smem;                  // [64][256] bf16, XOR-swizzled

  const int tid  = threadIdx.x;
  const int lane = tid & 63;
  const int wave = tid >> 6;
  const int l15  = lane & 15;
  const int lhi  = lane >> 4;
  const long rowbase = (long)blockIdx.x * 64;

  // ---- stage X tile: 64x128 f32 (contiguous 32KB) -> bf16 LDS ----
  const float4* Xblk = reinterpret_cast<const float4*>(X + rowbase * 128);
  #pragma unroll
  for (int it = 0; it < 8; ++it) {
    int idx4 = it * 256 + tid;                // coalesced float4 index
    float4 f = Xblk[idx4];
    int e0  = idx4 * 4;
    int row = e0 >> 7;
    int col = e0 & 127;
    int sidx = (row * 128 + col) ^ ((row & 7) << 3);   // 16B-granular XOR swizzle
    ushort4 u;
    u.x = f2b(f.x); u.y = f2b(f.y); u.z = f2b(f.z); u.w = f2b(f.w);
    *reinterpret_cast<ushort4*>(&Xs[sidx]) = u;
  }
  __syncthreads();

  // ---- A-fragments (X) into registers: afrag[mt][ks] ----
  short8 afrag[4][4];
  #pragma unroll
  for (int mt = 0; mt < 4; ++mt) {
    int row = mt * 16 + l15;
    #pragma unroll
    for (int ks = 0; ks < 4; ++ks) {
      int sidx = (row * 128 + ks * 32 + lhi * 8) ^ ((row & 7) << 3);
      afrag[mt][ks] = *reinterpret_cast<const short8*>(&Xs[sidx]);
    }
  }
  __syncthreads();   // all waves done reading Xs; Ys may now overwrite it

  const f32x4 vzero = {0.f, 0.f, 0.f, 0.f};

  // ---- stage 1: V and G for this wave's 64-col band, gate, write Ys ----
  #pragma unroll
  for (int t = 0; t < 4; ++t) {
    int c0 = (wave * 4 + t) * 16;
    const unsigned short* WVrow = W1T + (c0 + l15) * 128 + lhi * 8;
    const unsigned short* WGrow = WVrow + 256 * 128;
    f32x4 accV[4], accG[4];
    #pragma unroll
    for (int mt = 0; mt < 4; ++mt) { accV[mt] = vzero; accG[mt] = vzero; }
    #pragma unroll
    for (int ks = 0; ks < 4; ++ks) {
      short8 bV = *reinterpret_cast<const short8*>(WVrow + ks * 32);
      short8 bG = *reinterpret_cast<const short8*>(WGrow + ks * 32);
      #pragma unroll
      for (int mt = 0; mt < 4; ++mt) {
        accV[mt] = __builtin_amdgcn_mfma_f32_16x16x32_bf16(afrag[mt][ks], bV, accV[mt], 0, 0, 0);
        accG[mt] = __builtin_amdgcn_mfma_f32_16x16x32_bf16(afrag[mt][ks], bG, accG[mt], 0, 0, 0);
      }
    }
    float bgval = bg2[c0 + l15];
    #pragma unroll
    for (int mt = 0; mt < 4; ++mt) {
      #pragma unroll
      for (int r = 0; r < 4; ++r) {
        int row = mt * 16 + lhi * 4 + r;      // C/D layout: col=lane&15, row=(lane>>4)*4+r
        float z = accG[mt][r] + bgval;
        float g = 1.0f / (1.0f + __expf(-z));
        float y = g * accV[mt][r];
        int sidx = (row * 256 + c0 + l15) ^ ((row & 7) << 3);
        Ys[sidx] = f2b(y);
      }
    }
  }
  __syncthreads();

  // ---- stage 2: Out = Ys @ Wo + bo ----
  f32x4 acc2[2][4];
  #pragma unroll
  for (int nn = 0; nn < 2; ++nn)
    #pragma unroll
    for (int mt = 0; mt < 4; ++mt) acc2[nn][mt] = vzero;

  int o0 = wave * 16;                          // wave's output cols: o0.. and 64+o0..
  #pragma unroll
  for (int ks = 0; ks < 8; ++ks) {
    short8 b0 = *reinterpret_cast<const short8*>(WoT + (o0 + l15) * 256 + ks * 32 + lhi * 8);
    short8 b1 = *reinterpret_cast<const short8*>(WoT + (64 + o0 + l15) * 256 + ks * 32 + lhi * 8);
    #pragma unroll
    for (int mt = 0; mt < 4; ++mt) {
      int row = mt * 16 + l15;
      int sidx = (row * 256 + ks * 32 + lhi * 8) ^ ((row & 7) << 3);
      short8 a = *reinterpret_cast<const short8*>(&Ys[sidx]);
      acc2[0][mt] = __builtin_amdgcn_mfma_f32_16x16x32_bf16(a, b0, acc2[0][mt], 0, 0, 0);
      acc2[1][mt] = __builtin_amdgcn_mfma_f32_16x16x32_bf16(a, b1, acc2[1][mt], 0, 0, 0);
    }
  }
  #pragma unroll
  for (int nn = 0; nn < 2; ++nn) {
    int o = nn * 64 + o0 + l15;
    float bov = bo[o];
    #pragma unroll
    for (int mt = 0; mt < 4; ++mt) {
      #pragma unroll
      for (int r = 0; r < 4; ++r) {
        long row = rowbase + mt * 16 + lhi * 4 + r;
        Out[row * 128 + o] = acc2[nn][mt][r] + bov;
      }
    }
  }
}

extern "C" void kernel_launch(void* const* d_in, const int* in_sizes, int n_in,
                              void* d_out, int out_size, void* d_ws, size_t ws_size,
                              hipStream_t stream) {
  // inputs: 0 inter_edges, 1 ab_mask, 2 at_mask, 3 Wq, 4 Wk, 5 Wv, 6 Web,
  //         7 Wg, 8 bg, 9 Wo, 10 bo   (Wq/Wk/Web/masks mathematically unused)
  const float* X   = (const float*)d_in[0];
  const float* Wv  = (const float*)d_in[5];
  const float* Wg  = (const float*)d_in[7];
  const float* bg  = (const float*)d_in[8];
  const float* Wo  = (const float*)d_in[9];
  const float* bo  = (const float*)d_in[10];

  unsigned short* W1T = (unsigned short*)d_ws;            // 512*128 bf16
  unsigned short* WoT = W1T + 512 * 128;                  // 128*256 bf16
  float*          bg2 = (float*)(WoT + 128 * 256);        // 256 f32

  prep_kernel<<<(65536 + 32768 + 256 + 255) / 256 + 1, 256, 0, stream>>>(
      Wv, Wg, bg, Wo, W1T, WoT, bg2);

  float* Out = (float*)d_out;
  fused_kernel<<<1024, 256, 0, stream>>>(X, W1T, WoT, bg2, bo, Out);
}

// Round 3
// 147.191 us; speedup vs baseline: 1.1155x; 1.1155x over previous
//
#include <hip/hip_runtime.h>
#include <hip/hip_bf16.h>

typedef __attribute__((ext_vector_type(8))) short short8;
typedef __attribute__((ext_vector_type(4))) float f32x4;

__device__ __forceinline__ unsigned short f2b(float x) {
  union { float f; unsigned u; } v; v.f = x;
  unsigned r = v.u + 0x7fffu + ((v.u >> 16) & 1u);
  return (unsigned short)(r >> 16);
}

// pack 8 f32 -> 8 bf16 (RNE) via v_cvt_pk_bf16_f32
__device__ __forceinline__ short8 pack8(float4 a, float4 b) {
  union { __hip_bfloat162 h[4]; short8 s; } u;
  u.h[0] = __float22bfloat162_rn(float2{a.x, a.y});
  u.h[1] = __float22bfloat162_rn(float2{a.z, a.w});
  u.h[2] = __float22bfloat162_rn(float2{b.x, b.y});
  u.h[3] = __float22bfloat162_rn(float2{b.z, b.w});
  return u.s;
}

// ---- prep: transpose + bf16-convert weights into workspace ----
// Source-coalesced reads. W1T [512][128]: rows 0..255 = Wv^T; rows 256..511 =
// Wg^T with columns pre-permuted so gate channel for output c=h*64+d is at
// row 256+c (gate source col g = d*4+h => dest row 256 + (g&3)*64 + (g>>2)).
// WoT [128][256] = Wo^T.  bg2[256] = permuted gate bias.
__global__ __launch_bounds__(256) void prep_kernel(
    const float* __restrict__ Wv, const float* __restrict__ Wg,
    const float* __restrict__ bgv, const float* __restrict__ Wo,
    unsigned short* __restrict__ W1T, unsigned short* __restrict__ WoT,
    float* __restrict__ bg2)
{
  int t = blockIdx.x * 256 + threadIdx.x;
  if (t < 32768) {                      // Wv: src [e][c]
    int e = t >> 8, c = t & 255;
    W1T[c * 128 + e] = f2b(Wv[t]);
  } else if (t < 65536) {               // Wg: src [e][g]
    int s = t - 32768;
    int e = s >> 8, g = s & 255;
    int cc = ((g & 3) << 6) + (g >> 2); // cc = h*64+d
    W1T[(256 + cc) * 128 + e] = f2b(Wg[s]);
  } else if (t < 65536 + 32768) {       // Wo: src [c][o]
    int s = t - 65536;
    int c = s >> 7, o = s & 127;
    WoT[o * 256 + c] = f2b(Wo[s]);
  } else if (t < 65536 + 32768 + 256) {
    int g = t - (65536 + 32768);
    bg2[((g & 3) << 6) + (g >> 2)] = bgv[g];
  }
}

// ---- fused: per 64-row tile: V/G GEMM -> sigmoid*V -> @Wo + bo ----
// A-fragments loaded DIRECTLY from global (8 contiguous f32 per lane match
// the mfma A-layout), converted in-register. No X staging, no staging
// barriers: single __syncthreads for the Ys exchange. LDS = 32KB (Ys only).
__global__ __launch_bounds__(256) void fused_kernel(
    const float* __restrict__ X,              // [65536][128] f32
    const unsigned short* __restrict__ W1T,   // [512][128] bf16
    const unsigned short* __restrict__ WoT,   // [128][256] bf16
    const float* __restrict__ bg2,            // [256]
    const float* __restrict__ bo,             // [128]
    float* __restrict__ Out)                  // [65536][128] f32
{
  __shared__ unsigned short Ys[64 * 256];     // 32KB, XOR-swizzled rows

  const int tid  = threadIdx.x;
  const int lane = tid & 63;
  const int wave = tid >> 6;
  const int l15  = lane & 15;
  const int lhi  = lane >> 4;
  const long rowbase = (long)blockIdx.x * 64;

  // ---- A-fragments (X) direct global -> registers: afrag[mt][ks] ----
  // A layout (16x16x32): lane holds row=l&15, k=(l>>4)*8+0..7 (8 contig f32).
  short8 afrag[4][4];
  #pragma unroll
  for (int mt = 0; mt < 4; ++mt) {
    const float* rowp = X + (rowbase + mt * 16 + l15) * 128 + lhi * 8;
    #pragma unroll
    for (int ks = 0; ks < 4; ++ks) {
      float4 fa = *reinterpret_cast<const float4*>(rowp + ks * 32);
      float4 fb = *reinterpret_cast<const float4*>(rowp + ks * 32 + 4);
      afrag[mt][ks] = pack8(fa, fb);
    }
  }

  const f32x4 vzero = {0.f, 0.f, 0.f, 0.f};

  // ---- stage 1: V and G for this wave's 64-col band, gate, write Ys ----
  #pragma unroll
  for (int t = 0; t < 4; ++t) {
    int c0 = (wave * 4 + t) * 16;
    const unsigned short* WVrow = W1T + (c0 + l15) * 128 + lhi * 8;
    const unsigned short* WGrow = WVrow + 256 * 128;
    f32x4 accV[4], accG[4];
    #pragma unroll
    for (int mt = 0; mt < 4; ++mt) { accV[mt] = vzero; accG[mt] = vzero; }
    #pragma unroll
    for (int ks = 0; ks < 4; ++ks) {
      short8 bV = *reinterpret_cast<const short8*>(WVrow + ks * 32);
      short8 bG = *reinterpret_cast<const short8*>(WGrow + ks * 32);
      #pragma unroll
      for (int mt = 0; mt < 4; ++mt) {
        accV[mt] = __builtin_amdgcn_mfma_f32_16x16x32_bf16(afrag[mt][ks], bV, accV[mt], 0, 0, 0);
        accG[mt] = __builtin_amdgcn_mfma_f32_16x16x32_bf16(afrag[mt][ks], bG, accG[mt], 0, 0, 0);
      }
    }
    float bgval = bg2[c0 + l15];
    #pragma unroll
    for (int mt = 0; mt < 4; ++mt) {
      #pragma unroll
      for (int r = 0; r < 4; ++r) {
        int row = mt * 16 + lhi * 4 + r;      // C/D layout: col=lane&15, row=(lane>>4)*4+r
        float z = accG[mt][r] + bgval;
        float g = 1.0f / (1.0f + __expf(-z));
        float y = g * accV[mt][r];
        int sidx = (row * 256 + c0 + l15) ^ ((row & 7) << 3);
        Ys[sidx] = f2b(y);
      }
    }
  }
  __syncthreads();

  // ---- stage 2: Out = Ys @ Wo + bo ----
  f32x4 acc2[2][4];
  #pragma unroll
  for (int nn = 0; nn < 2; ++nn)
    #pragma unroll
    for (int mt = 0; mt < 4; ++mt) acc2[nn][mt] = vzero;

  int o0 = wave * 16;                          // wave's output cols: o0.. and 64+o0..
  #pragma unroll
  for (int ks = 0; ks < 8; ++ks) {
    short8 b0 = *reinterpret_cast<const short8*>(WoT + (o0 + l15) * 256 + ks * 32 + lhi * 8);
    short8 b1 = *reinterpret_cast<const short8*>(WoT + (64 + o0 + l15) * 256 + ks * 32 + lhi * 8);
    #pragma unroll
    for (int mt = 0; mt < 4; ++mt) {
      int row = mt * 16 + l15;
      int sidx = (row * 256 + ks * 32 + lhi * 8) ^ ((row & 7) << 3);
      short8 a = *reinterpret_cast<const short8*>(&Ys[sidx]);
      acc2[0][mt] = __builtin_amdgcn_mfma_f32_16x16x32_bf16(a, b0, acc2[0][mt], 0, 0, 0);
      acc2[1][mt] = __builtin_amdgcn_mfma_f32_16x16x32_bf16(a, b1, acc2[1][mt], 0, 0, 0);
    }
  }
  #pragma unroll
  for (int nn = 0; nn < 2; ++nn) {
    int o = nn * 64 + o0 + l15;
    float bov = bo[o];
    #pragma unroll
    for (int mt = 0; mt < 4; ++mt) {
      #pragma unroll
      for (int r = 0; r < 4; ++r) {
        long row = rowbase + mt * 16 + lhi * 4 + r;
        Out[row * 128 + o] = acc2[nn][mt][r] + bov;
      }
    }
  }
}

extern "C" void kernel_launch(void* const* d_in, const int* in_sizes, int n_in,
                              void* d_out, int out_size, void* d_ws, size_t ws_size,
                              hipStream_t stream) {
  // inputs: 0 inter_edges, 1 ab_mask, 2 at_mask, 3 Wq, 4 Wk, 5 Wv, 6 Web,
  //         7 Wg, 8 bg, 9 Wo, 10 bo   (Wq/Wk/Web/masks mathematically unused)
  const float* X   = (const float*)d_in[0];
  const float* Wv  = (const float*)d_in[5];
  const float* Wg  = (const float*)d_in[7];
  const float* bg  = (const float*)d_in[8];
  const float* Wo  = (const float*)d_in[9];
  const float* bo  = (const float*)d_in[10];

  unsigned short* W1T = (unsigned short*)d_ws;            // 512*128 bf16
  unsigned short* WoT = W1T + 512 * 128;                  // 128*256 bf16
  float*          bg2 = (float*)(WoT + 128 * 256);        // 256 f32

  prep_kernel<<<386, 256, 0, stream>>>(Wv, Wg, bg, Wo, W1T, WoT, bg2);

  float* Out = (float*)d_out;
  fused_kernel<<<1024, 256, 0, stream>>>(X, W1T, WoT, bg2, bo, Out);
}

// Round 4
// 142.591 us; speedup vs baseline: 1.1514x; 1.0323x over previous
//
#include <hip/hip_runtime.h>
#include <hip/hip_bf16.h>

typedef __attribute__((ext_vector_type(8))) short short8;
typedef __attribute__((ext_vector_type(4))) float f32x4;

__device__ __forceinline__ unsigned short f2b(float x) {
  union { float f; unsigned u; } v; v.f = x;
  unsigned r = v.u + 0x7fffu + ((v.u >> 16) & 1u);
  return (unsigned short)(r >> 16);
}

// pack 4 f32 -> 4 bf16 (RNE) via 2x v_cvt_pk_bf16_f32
__device__ __forceinline__ ushort4 pack4(float4 f) {
  union { __hip_bfloat162 h[2]; ushort4 s; } u;
  u.h[0] = __float22bfloat162_rn(float2{f.x, f.y});
  u.h[1] = __float22bfloat162_rn(float2{f.z, f.w});
  return u.s;
}

// ---- prep: transpose + bf16-convert weights into workspace ----
// Source-coalesced reads. W1T [512][128]: rows 0..255 = Wv^T; rows 256..511 =
// Wg^T with columns pre-permuted so gate channel for output c=h*64+d is at
// row 256+c (gate source col g = d*4+h => dest row 256 + (g&3)*64 + (g>>2)).
// WoT [128][256] = Wo^T.  bg2[256] = permuted gate bias.
__global__ __launch_bounds__(256) void prep_kernel(
    const float* __restrict__ Wv, const float* __restrict__ Wg,
    const float* __restrict__ bgv, const float* __restrict__ Wo,
    unsigned short* __restrict__ W1T, unsigned short* __restrict__ WoT,
    float* __restrict__ bg2)
{
  int t = blockIdx.x * 256 + threadIdx.x;
  if (t < 32768) {                      // Wv: src [e][c]
    int e = t >> 8, c = t & 255;
    W1T[c * 128 + e] = f2b(Wv[t]);
  } else if (t < 65536) {               // Wg: src [e][g]
    int s = t - 32768;
    int e = s >> 8, g = s & 255;
    int cc = ((g & 3) << 6) + (g >> 2); // cc = h*64+d
    W1T[(256 + cc) * 128 + e] = f2b(Wg[s]);
  } else if (t < 65536 + 32768) {       // Wo: src [c][o]
    int s = t - 65536;
    int c = s >> 7, o = s & 127;
    WoT[o * 256 + c] = f2b(Wo[s]);
  } else if (t < 65536 + 32768 + 256) {
    int g = t - (65536 + 32768);
    bg2[((g & 3) << 6) + (g >> 2)] = bgv[g];
  }
}

// ---- fused: per 32-row tile: V/G GEMM -> sigmoid*V -> @Wo + bo ----
// 32-row tiles (grid 2048): LDS 24KB (Xs 8KB + Ys 16KB separate -> only 2
// barriers), afrag halved to 32 VGPR. Target ~5-6 blocks/CU resident.
__global__ __launch_bounds__(256) void fused_kernel(
    const float* __restrict__ X,              // [65536][128] f32
    const unsigned short* __restrict__ W1T,   // [512][128] bf16
    const unsigned short* __restrict__ WoT,   // [128][256] bf16
    const float* __restrict__ bg2,            // [256]
    const float* __restrict__ bo,             // [128]
    float* __restrict__ Out)                  // [65536][128] f32
{
  __shared__ unsigned short Xs[32 * 128];     // 8KB bf16, XOR-swizzled rows
  __shared__ unsigned short Ys[32 * 256];     // 16KB bf16, XOR-swizzled rows

  const int tid  = threadIdx.x;
  const int lane = tid & 63;
  const int wave = tid >> 6;
  const int l15  = lane & 15;
  const int lhi  = lane >> 4;
  const long rowbase = (long)blockIdx.x * 32;

  // ---- stage X tile: 32x128 f32 (contiguous 16KB) -> bf16 LDS ----
  const float4* Xblk = reinterpret_cast<const float4*>(X + rowbase * 128);
  #pragma unroll
  for (int it = 0; it < 4; ++it) {
    int idx4 = it * 256 + tid;                // coalesced float4 index
    float4 f = Xblk[idx4];
    int e0  = idx4 * 4;
    int row = e0 >> 7;
    int col = e0 & 127;
    int sidx = (row * 128 + col) ^ ((row & 7) << 3);   // 16B-granular XOR swizzle
    *reinterpret_cast<ushort4*>(&Xs[sidx]) = pack4(f);
  }
  __syncthreads();

  // ---- A-fragments (X) into registers: afrag[mt][ks] ----
  short8 afrag[2][4];
  #pragma unroll
  for (int mt = 0; mt < 2; ++mt) {
    int row = mt * 16 + l15;
    #pragma unroll
    for (int ks = 0; ks < 4; ++ks) {
      int sidx = (row * 128 + ks * 32 + lhi * 8) ^ ((row & 7) << 3);
      afrag[mt][ks] = *reinterpret_cast<const short8*>(&Xs[sidx]);
    }
  }

  const f32x4 vzero = {0.f, 0.f, 0.f, 0.f};

  // ---- stage 1: V and G for this wave's 64-col band, gate, write Ys ----
  #pragma unroll
  for (int t = 0; t < 4; ++t) {
    int c0 = (wave * 4 + t) * 16;
    const unsigned short* WVrow = W1T + (c0 + l15) * 128 + lhi * 8;
    const unsigned short* WGrow = WVrow + 256 * 128;
    f32x4 accV[2], accG[2];
    #pragma unroll
    for (int mt = 0; mt < 2; ++mt) { accV[mt] = vzero; accG[mt] = vzero; }
    #pragma unroll
    for (int ks = 0; ks < 4; ++ks) {
      short8 bV = *reinterpret_cast<const short8*>(WVrow + ks * 32);
      short8 bG = *reinterpret_cast<const short8*>(WGrow + ks * 32);
      #pragma unroll
      for (int mt = 0; mt < 2; ++mt) {
        accV[mt] = __builtin_amdgcn_mfma_f32_16x16x32_bf16(afrag[mt][ks], bV, accV[mt], 0, 0, 0);
        accG[mt] = __builtin_amdgcn_mfma_f32_16x16x32_bf16(afrag[mt][ks], bG, accG[mt], 0, 0, 0);
      }
    }
    float bgval = bg2[c0 + l15];
    #pragma unroll
    for (int mt = 0; mt < 2; ++mt) {
      #pragma unroll
      for (int r = 0; r < 4; ++r) {
        int row = mt * 16 + lhi * 4 + r;      // C/D layout: col=lane&15, row=(lane>>4)*4+r
        float z = accG[mt][r] + bgval;
        float g = 1.0f / (1.0f + __expf(-z));
        float y = g * accV[mt][r];
        int sidx = (row * 256 + c0 + l15) ^ ((row & 7) << 3);
        Ys[sidx] = f2b(y);
      }
    }
  }
  __syncthreads();

  // ---- stage 2: Out = Ys @ Wo + bo ----
  f32x4 acc2[2][2];
  #pragma unroll
  for (int nn = 0; nn < 2; ++nn)
    #pragma unroll
    for (int mt = 0; mt < 2; ++mt) acc2[nn][mt] = vzero;

  int o0 = wave * 16;                          // wave's output cols: o0.. and 64+o0..
  #pragma unroll
  for (int ks = 0; ks < 8; ++ks) {
    short8 b0 = *reinterpret_cast<const short8*>(WoT + (o0 + l15) * 256 + ks * 32 + lhi * 8);
    short8 b1 = *reinterpret_cast<const short8*>(WoT + (64 + o0 + l15) * 256 + ks * 32 + lhi * 8);
    #pragma unroll
    for (int mt = 0; mt < 2; ++mt) {
      int row = mt * 16 + l15;
      int sidx = (row * 256 + ks * 32 + lhi * 8) ^ ((row & 7) << 3);
      short8 a = *reinterpret_cast<const short8*>(&Ys[sidx]);
      acc2[0][mt] = __builtin_amdgcn_mfma_f32_16x16x32_bf16(a, b0, acc2[0][mt], 0, 0, 0);
      acc2[1][mt] = __builtin_amdgcn_mfma_f32_16x16x32_bf16(a, b1, acc2[1][mt], 0, 0, 0);
    }
  }
  #pragma unroll
  for (int nn = 0; nn < 2; ++nn) {
    int o = nn * 64 + o0 + l15;
    float bov = bo[o];
    #pragma unroll
    for (int mt = 0; mt < 2; ++mt) {
      #pragma unroll
      for (int r = 0; r < 4; ++r) {
        long row = rowbase + mt * 16 + lhi * 4 + r;
        Out[row * 128 + o] = acc2[nn][mt][r] + bov;
      }
    }
  }
}

extern "C" void kernel_launch(void* const* d_in, const int* in_sizes, int n_in,
                              void* d_out, int out_size, void* d_ws, size_t ws_size,
                              hipStream_t stream) {
  // inputs: 0 inter_edges, 1 ab_mask, 2 at_mask, 3 Wq, 4 Wk, 5 Wv, 6 Web,
  //         7 Wg, 8 bg, 9 Wo, 10 bo   (Wq/Wk/Web/masks mathematically unused)
  const float* X   = (const float*)d_in[0];
  const float* Wv  = (const float*)d_in[5];
  const float* Wg  = (const float*)d_in[7];
  const float* bg  = (const float*)d_in[8];
  const float* Wo  = (const float*)d_in[9];
  const float* bo  = (const float*)d_in[10];

  unsigned short* W1T = (unsigned short*)d_ws;            // 512*128 bf16
  unsigned short* WoT = W1T + 512 * 128;                  // 128*256 bf16
  float*          bg2 = (float*)(WoT + 128 * 256);        // 256 f32

  prep_kernel<<<386, 256, 0, stream>>>(Wv, Wg, bg, Wo, W1T, WoT, bg2);

  float* Out = (float*)d_out;
  fused_kernel<<<2048, 256, 0, stream>>>(X, W1T, WoT, bg2, bo, Out);
}

// Round 5
// 122.445 us; speedup vs baseline: 1.3409x; 1.1645x over previous
//
#include <hip/hip_runtime.h>
#include <hip/hip_bf16.h>

typedef __attribute__((ext_vector_type(8))) short short8;
typedef __attribute__((ext_vector_type(4))) float f32x4;

__device__ __forceinline__ unsigned short f2b(float x) {
  union { float f; unsigned u; } v; v.f = x;
  unsigned r = v.u + 0x7fffu + ((v.u >> 16) & 1u);
  return (unsigned short)(r >> 16);
}

// pack 4 f32 -> 4 bf16 (RNE) via 2x v_cvt_pk_bf16_f32
__device__ __forceinline__ ushort4 pack4(float4 f) {
  union { __hip_bfloat162 h[2]; ushort4 s; } u;
  u.h[0] = __float22bfloat162_rn(float2{f.x, f.y});
  u.h[1] = __float22bfloat162_rn(float2{f.z, f.w});
  return u.s;
}

// ---- prep: transpose + bf16-convert weights into workspace ----
// W1T [512][128]: rows 0..255 = Wv^T; rows 256..511 = Wg^T with columns
// pre-permuted so gate channel for output c=h*64+d sits at row 256+c
// (gate source col g = d*4+h => dest row 256 + (g&3)*64 + (g>>2)).
// WoT [128][256] = Wo^T.  bg2[256] = permuted gate bias.
__global__ __launch_bounds__(256) void prep_kernel(
    const float* __restrict__ Wv, const float* __restrict__ Wg,
    const float* __restrict__ bgv, const float* __restrict__ Wo,
    unsigned short* __restrict__ W1T, unsigned short* __restrict__ WoT,
    float* __restrict__ bg2)
{
  int t = blockIdx.x * 256 + threadIdx.x;
  if (t < 32768) {                      // Wv: src [e][c]
    int e = t >> 8, c = t & 255;
    W1T[c * 128 + e] = f2b(Wv[t]);
  } else if (t < 65536) {               // Wg: src [e][g]
    int s = t - 32768;
    int e = s >> 8, g = s & 255;
    int cc = ((g & 3) << 6) + (g >> 2); // cc = h*64+d
    W1T[(256 + cc) * 128 + e] = f2b(Wg[s]);
  } else if (t < 65536 + 32768) {       // Wo: src [c][o]
    int s = t - 65536;
    int c = s >> 7, o = s & 127;
    WoT[o * 256 + c] = f2b(Wo[s]);
  } else if (t < 65536 + 32768 + 256) {
    int g = t - (65536 + 32768);
    bg2[((g & 3) << 6) + (g >> 2)] = bgv[g];
  }
}

// ---- fused, persistent-weight: 8 waves, weights in VGPRs, 8x32-row tiles ----
// Main loop has ZERO global weight loads; X prefetched one tile ahead;
// double-buffered Xs+Ys => ONE barrier per iteration.
__global__ __launch_bounds__(512, 2) void fused_kernel(
    const float* __restrict__ X,              // [65536][128] f32
    const unsigned short* __restrict__ W1T,   // [512][128] bf16
    const unsigned short* __restrict__ WoT,   // [128][256] bf16
    const float* __restrict__ bg2,            // [256]
    const float* __restrict__ bo,             // [128]
    float* __restrict__ Out)                  // [65536][128] f32
{
  __shared__ unsigned short Xs[2][32 * 128];  // 2 x 8KB, XOR-swizzled
  __shared__ unsigned short Ys[2][32 * 256];  // 2 x 16KB, XOR-swizzled

  const int tid  = threadIdx.x;
  const int lane = tid & 63;
  const int wave = tid >> 6;                  // 0..7
  const int l15  = lane & 15;
  const int lhi  = lane >> 4;
  const long rowbase0 = (long)blockIdx.x * 256;

  // ---- prologue: persistent weights into registers (once per block) ----
  short8 wS1[2][4][2];                        // [c-tile t][ks][V=0,G=1]
  float  bgt[2];
  #pragma unroll
  for (int t = 0; t < 2; ++t) {
    int c0 = (wave * 2 + t) * 16;
    const unsigned short* base = W1T + (c0 + l15) * 128 + lhi * 8;
    #pragma unroll
    for (int ks = 0; ks < 4; ++ks) {
      wS1[t][ks][0] = *reinterpret_cast<const short8*>(base + ks * 32);
      wS1[t][ks][1] = *reinterpret_cast<const short8*>(base + ks * 32 + 256 * 128);
    }
    bgt[t] = bg2[c0 + l15];
  }
  short8 wS2[8];
  const int o0 = wave * 16;                   // this wave's 16 output cols
  #pragma unroll
  for (int ks = 0; ks < 8; ++ks)
    wS2[ks] = *reinterpret_cast<const short8*>(WoT + (o0 + l15) * 256 + ks * 32 + lhi * 8);
  const float bov = bo[o0 + l15];

  // ---- stage tile 0 into Xs[0] ----
  {
    const float4* Xp = reinterpret_cast<const float4*>(X + rowbase0 * 128);
    #pragma unroll
    for (int it = 0; it < 2; ++it) {
      int idx4 = it * 512 + tid;              // 1024 float4 per 32x128 tile
      float4 f = Xp[idx4];
      int row = idx4 >> 5;
      int col = (idx4 & 31) * 4;
      int sidx = (row * 128 + col) ^ ((row & 7) << 3);
      *reinterpret_cast<ushort4*>(&Xs[0][sidx]) = pack4(f);
    }
  }
  __syncthreads();

  const f32x4 vzero = {0.f, 0.f, 0.f, 0.f};

  for (int i = 0; i < 8; ++i) {
    const int cur = i & 1;

    // ---- A: X fragments from Xs[cur] ----
    short8 afrag[2][4];
    #pragma unroll
    for (int mt = 0; mt < 2; ++mt) {
      int row = mt * 16 + l15;
      #pragma unroll
      for (int ks = 0; ks < 4; ++ks) {
        int sidx = (row * 128 + ks * 32 + lhi * 8) ^ ((row & 7) << 3);
        afrag[mt][ks] = *reinterpret_cast<const short8*>(&Xs[cur][sidx]);
      }
    }

    // issue next-tile X loads early (latency hides under stage-1 MFMA)
    float4 f0, f1;
    if (i < 7) {
      const float4* Xp = reinterpret_cast<const float4*>(X + (rowbase0 + (i + 1) * 32) * 128);
      f0 = Xp[tid];
      f1 = Xp[512 + tid];
    }

    // ---- stage 1: V/G MFMA (in-reg weights), gate, write Ys[cur] ----
    #pragma unroll
    for (int t = 0; t < 2; ++t) {
      int c0 = (wave * 2 + t) * 16;
      f32x4 accV[2] = {vzero, vzero}, accG[2] = {vzero, vzero};
      #pragma unroll
      for (int ks = 0; ks < 4; ++ks) {
        #pragma unroll
        for (int mt = 0; mt < 2; ++mt) {
          accV[mt] = __builtin_amdgcn_mfma_f32_16x16x32_bf16(afrag[mt][ks], wS1[t][ks][0], accV[mt], 0, 0, 0);
          accG[mt] = __builtin_amdgcn_mfma_f32_16x16x32_bf16(afrag[mt][ks], wS1[t][ks][1], accG[mt], 0, 0, 0);
        }
      }
      #pragma unroll
      for (int mt = 0; mt < 2; ++mt) {
        #pragma unroll
        for (int r = 0; r < 4; ++r) {
          int row = mt * 16 + lhi * 4 + r;    // C/D: col=lane&15, row=(lane>>4)*4+r
          float z = accG[mt][r] + bgt[t];
          float g = 1.0f / (1.0f + __expf(-z));
          float y = g * accV[mt][r];
          int sidx = (row * 256 + c0 + l15) ^ ((row & 7) << 3);
          Ys[cur][sidx] = f2b(y);
        }
      }
    }

    // write next tile into Xs[cur^1] (loads issued above have drained by now)
    if (i < 7) {
      int idx4 = tid;
      int row = idx4 >> 5, col = (idx4 & 31) * 4;
      int sidx = (row * 128 + col) ^ ((row & 7) << 3);
      *reinterpret_cast<ushort4*>(&Xs[cur ^ 1][sidx]) = pack4(f0);
      idx4 = 512 + tid;
      row = idx4 >> 5; col = (idx4 & 31) * 4;
      sidx = (row * 128 + col) ^ ((row & 7) << 3);
      *reinterpret_cast<ushort4*>(&Xs[cur ^ 1][sidx]) = pack4(f1);
    }

    __syncthreads();   // Ys[cur] + Xs[cur^1] ready; Xs[cur] now dead

    // ---- stage 2: Out tile = Ys[cur] @ Wo + bo (in-reg weights) ----
    f32x4 acc2[2] = {vzero, vzero};
    #pragma unroll
    for (int ks = 0; ks < 8; ++ks) {
      #pragma unroll
      for (int mt = 0; mt < 2; ++mt) {
        int row = mt * 16 + l15;
        int sidx = (row * 256 + ks * 32 + lhi * 8) ^ ((row & 7) << 3);
        short8 a = *reinterpret_cast<const short8*>(&Ys[cur][sidx]);
        acc2[mt] = __builtin_amdgcn_mfma_f32_16x16x32_bf16(a, wS2[ks], acc2[mt], 0, 0, 0);
      }
    }
    const long rowb = rowbase0 + (long)i * 32;
    #pragma unroll
    for (int mt = 0; mt < 2; ++mt) {
      #pragma unroll
      for (int r = 0; r < 4; ++r) {
        Out[(rowb + mt * 16 + lhi * 4 + r) * 128 + o0 + l15] = acc2[mt][r] + bov;
      }
    }
    // no second barrier: next A writes Ys[cur^1] (double-buffered) and only
    // reads Xs[cur^1], whose writes were sequenced before this barrier.
  }
}

extern "C" void kernel_launch(void* const* d_in, const int* in_sizes, int n_in,
                              void* d_out, int out_size, void* d_ws, size_t ws_size,
                              hipStream_t stream) {
  // inputs: 0 inter_edges, 1 ab_mask, 2 at_mask, 3 Wq, 4 Wk, 5 Wv, 6 Web,
  //         7 Wg, 8 bg, 9 Wo, 10 bo   (Wq/Wk/Web/masks mathematically unused)
  const float* X   = (const float*)d_in[0];
  const float* Wv  = (const float*)d_in[5];
  const float* Wg  = (const float*)d_in[7];
  const float* bg  = (const float*)d_in[8];
  const float* Wo  = (const float*)d_in[9];
  const float* bo  = (const float*)d_in[10];

  unsigned short* W1T = (unsigned short*)d_ws;            // 512*128 bf16
  unsigned short* WoT = W1T + 512 * 128;                  // 128*256 bf16
  float*          bg2 = (float*)(WoT + 128 * 256);        // 256 f32

  prep_kernel<<<386, 256, 0, stream>>>(Wv, Wg, bg, Wo, W1T, WoT, bg2);

  float* Out = (float*)d_out;
  fused_kernel<<<256, 512, 0, stream>>>(X, W1T, WoT, bg2, bo, Out);
}